// Round 15
// baseline (211.794 us; speedup 1.0000x reference)
//
#include <hip/hip_runtime.h>

typedef unsigned short u16;
typedef short bf16x8 __attribute__((ext_vector_type(8)));
typedef float f32x4 __attribute__((ext_vector_type(4)));
typedef unsigned int u32;
typedef u32 u32x4 __attribute__((ext_vector_type(4)));

#define B_ 4
#define S_ 2048
#define D_ 1024
#define H_ 16
#define DH_ 64
#define M_ 8192   // B*S
#define SCL2E 0.1803368801111244f  /* 0.125 * log2(e), folded into Q at gemm1 */

__device__ __forceinline__ u16 f2b(float f) {
  union { float f; unsigned int u; } v; v.f = f;
  unsigned int u = v.u;
  unsigned int r = (u + 0x7FFFu + ((u >> 16) & 1u)) >> 16;
  return (u16)r;
}

// async global->LDS, 16B per lane; lds dst must be the WAVE-UNIFORM base
__device__ __forceinline__ void gload16(const void* g, void* l) {
  __builtin_amdgcn_global_load_lds(
      (const __attribute__((address_space(1))) unsigned int*)g,
      (__attribute__((address_space(3))) unsigned int*)l,
      16, 0, 0);
}

// pack two f32 -> two bf16 (RNE) in one VALU op
__device__ __forceinline__ u32 cvt_pk_bf16(float lo, float hi) {
  u32 r;
  asm("v_cvt_pk_bf16_f32 %0, %1, %2" : "=v"(r) : "v"(lo), "v"(hi));
  return r;
}

// ---------------- elementwise fp32 -> bf16 ----------------
struct __attribute__((aligned(8))) u16x4 { u16 x, y, z, w; };

__global__ void cvt_f32_bf16(const float* __restrict__ in, u16* __restrict__ out, int n) {
  int i = (blockIdx.x * blockDim.x + threadIdx.x) * 4;
  if (i >= n) return;
  float4 v = *(const float4*)(in + i);
  u16x4 o; o.x = f2b(v.x); o.y = f2b(v.y); o.z = f2b(v.z); o.w = f2b(v.w);
  *(u16x4*)(out + i) = o;
}

// ---------------- tiled transpose + convert: in[R][C] f32 -> out[C][R] bf16 ----------------
__global__ void transpose_cvt(const float* __restrict__ in, u16* __restrict__ out, int R, int C) {
  __shared__ float tile[32][33];
  int c0 = blockIdx.x * 32, r0 = blockIdx.y * 32;
  int tx = threadIdx.x, ty = threadIdx.y; // 32 x 8
#pragma unroll
  for (int j = 0; j < 32; j += 8)
    tile[ty + j][tx] = in[(size_t)(r0 + ty + j) * C + c0 + tx];
  __syncthreads();
#pragma unroll
  for (int j = 0; j < 32; j += 8)
    out[(size_t)(c0 + ty + j) * R + r0 + tx] = f2b(tile[tx][ty + j]);
}

// ---------------- proj GEMM (r12 proven 4-wave 128x128, counted vmcnt) ----------------
template <int MODE>
__global__ __launch_bounds__(256) void gemm_bt(
    const u16* __restrict__ A, const u16* __restrict__ BT,
    const float* __restrict__ bias, float* __restrict__ outf,
    u16* __restrict__ qb, u16* __restrict__ kb, u16* __restrict__ vtb,
    int Ncols, int Kdim) {
  __shared__ __attribute__((aligned(16))) u16 lsA[2][128 * 64];
  __shared__ __attribute__((aligned(16))) u16 lsB[2][128 * 64];
  const int t = threadIdx.x;
  const int lane = t & 63, w = t >> 6;
  const int lhi = lane >> 4, llo = lane & 15;

  const int gx = gridDim.x;
  const int lin = blockIdx.y * gx + blockIdx.x;
  const int nwg = gx * gridDim.y;
  const int sw = (lin & 7) * (nwg >> 3) + (lin >> 3);
  const int m0 = (sw / gx) * 128, n0 = (sw % gx) * 128;

  const int wr = (w >> 1) * 64, wc = (w & 1) * 64;

  const int r8 = lane >> 3;
  const int scolE = ((lane & 7) ^ r8) * 8;
  const int srow = w * 32 + r8;

  f32x4 acc[4][4] = {};
  const int nt = Kdim >> 6;

#define STAGE_G(buf, kk0)                                                        \
  _Pragma("unroll") for (int j = 0; j < 4; ++j) {                                \
    gload16(A + (size_t)(m0 + srow + j * 8) * Kdim + (kk0) + scolE,              \
            &lsA[buf][(w * 32 + j * 8) * 64]);                                   \
    gload16(BT + (size_t)(n0 + srow + j * 8) * Kdim + (kk0) + scolE,             \
            &lsB[buf][(w * 32 + j * 8) * 64]);                                   \
  }

  STAGE_G(0, 0)

  for (int tt = 0; tt < nt; ++tt) {
    const int cur = tt & 1;
    if (tt + 1 < nt) {
      STAGE_G(cur ^ 1, (tt + 1) << 6)
      asm volatile("s_waitcnt vmcnt(8)" ::: "memory");
    } else {
      asm volatile("s_waitcnt vmcnt(0)" ::: "memory");
    }
    __builtin_amdgcn_sched_barrier(0);
    __builtin_amdgcn_s_barrier();
    __builtin_amdgcn_sched_barrier(0);
#pragma unroll
    for (int kk = 0; kk < 2; ++kk) {
      bf16x8 af[4], bfr[4];
#pragma unroll
      for (int i = 0; i < 4; ++i) {
        int ra = wr + i * 16 + llo;
        af[i] = *(const bf16x8*)((const char*)&lsA[cur][ra * 64] +
                                 ((kk * 64 + lhi * 16) ^ ((ra & 7) << 4)));
        int rb = wc + i * 16 + llo;
        bfr[i] = *(const bf16x8*)((const char*)&lsB[cur][rb * 64] +
                                  ((kk * 64 + lhi * 16) ^ ((rb & 7) << 4)));
      }
#pragma unroll
      for (int mi = 0; mi < 4; ++mi)
#pragma unroll
        for (int ni = 0; ni < 4; ++ni)
          acc[mi][ni] = __builtin_amdgcn_mfma_f32_16x16x32_bf16(af[mi], bfr[ni], acc[mi][ni], 0, 0, 0);
    }
    __builtin_amdgcn_sched_barrier(0);
    __builtin_amdgcn_s_barrier();
  }
#undef STAGE_G

  if (MODE == 0) {
#pragma unroll
    for (int mi = 0; mi < 4; ++mi)
#pragma unroll
      for (int ni = 0; ni < 4; ++ni)
#pragma unroll
        for (int r = 0; r < 4; ++r) {
          int m = m0 + wr + mi * 16 + lhi * 4 + r;
          int n = n0 + wc + ni * 16 + llo;
          outf[(size_t)m * Ncols + n] = acc[mi][ni][r] + bias[n];
        }
  }
}

// ---------------- QKV GEMM: 256x256 4-phase/K-tile, counted vmcnt(6) ----------------
// 8 waves (2Mx4N), wave output 128x64 (acc[8][4]), BK=64, LDS 128KB:
// lsA/lsB[2 dbuf][2 half][128x64]. Each phase: vmcnt(6) -> s_barrier ->
// ds_read subtile -> stage 1 half-tile of tile kt+1 -> 16 MFMA (setprio).
// Invariant: half read at phase p was staged 4 phases ago with exactly 3
// half-tiles (6 loads) issued after it -> vmcnt(6) suffices; last tile peels
// to 6/4/2/0. No vmcnt(0) in main loop. Pre-swizzled global source, XOR read.
// XCD block swizzle. Q pre-scaled by SCL2E; V^T slot-permuted.
__global__ __launch_bounds__(512, 1) void gemm256(
    const u16* __restrict__ A, const u16* __restrict__ BT,
    const float* __restrict__ bias,
    u16* __restrict__ qb, u16* __restrict__ kb, u16* __restrict__ vtb,
    int Kdim) {
  __shared__ __attribute__((aligned(16))) u16 lsA[2][2][128 * 64];
  __shared__ __attribute__((aligned(16))) u16 lsB[2][2][128 * 64];
  const int t = threadIdx.x;
  const int lane = t & 63, w = t >> 6;
  const int lhi = lane >> 4, llo = lane & 15;

  const int gx = gridDim.x;
  const int lin = blockIdx.y * gx + blockIdx.x;
  const int nwg = gx * gridDim.y;
  const int sw = (lin & 7) * (nwg >> 3) + (lin >> 3);
  const int m0 = (sw / gx) * 256, n0 = (sw % gx) * 256;

  const int wr = w >> 2, wc = w & 3;            // wave: rows wr*128+[0,128), cols wc*64+[0,64)
  const int srowj = t >> 3;                     // 0..63
  const int scol = ((t & 7) ^ (srowj & 7)) * 8; // pre-swizzled source col (elems)
  const u16* gA = A + (size_t)m0 * Kdim;
  const u16* gB = BT + (size_t)n0 * Kdim;

  f32x4 acc[8][4] = {};
  const int nt = Kdim >> 6;

#define STG256(buf, h, kk0)                                                     \
  { const u16* gp = ((h) < 2 ? gA + (size_t)((h) * 128) * Kdim                  \
                             : gB + (size_t)(((h) - 2) * 128) * Kdim);          \
    u16* lp = ((h) < 2 ? &lsA[buf][(h)][0] : &lsB[buf][(h) - 2][0]);            \
    _Pragma("unroll") for (int j = 0; j < 2; ++j)                               \
      gload16(gp + (size_t)(j * 64 + srowj) * Kdim + (kk0) + scol,              \
              lp + j * 4096 + w * 512); }

  // prologue: tile 0, halves 0..3 (8 loads/thread in flight)
  STG256(0, 0, 0) STG256(0, 1, 0) STG256(0, 2, 0) STG256(0, 3, 0)

  bf16x8 af[4][2], bfr[2][2];

#define RDA256(c, mh)                                                            \
  _Pragma("unroll") for (int mi = 0; mi < 4; ++mi)                               \
  _Pragma("unroll") for (int kk = 0; kk < 2; ++kk) {                             \
    int rih = (mh) * 64 + mi * 16 + llo;                                         \
    af[mi][kk] = *(const bf16x8*)((const char*)&lsA[c][wr][0] + rih * 128 +      \
                                  ((kk * 64 + lhi * 16) ^ ((rih & 7) << 4)));    \
  }
#define RDB256(c, nh)                                                            \
  _Pragma("unroll") for (int ni = 0; ni < 2; ++ni)                               \
  _Pragma("unroll") for (int kk = 0; kk < 2; ++kk) {                             \
    int rih = (wc & 1) * 64 + (nh) * 32 + ni * 16 + llo;                         \
    bfr[ni][kk] = *(const bf16x8*)((const char*)&lsB[c][wc >> 1][0] + rih * 128 +\
                                   ((kk * 64 + lhi * 16) ^ ((rih & 7) << 4)));   \
  }
#define MFMA256(mh, nh)                                                          \
  __builtin_amdgcn_s_setprio(1);                                                 \
  _Pragma("unroll") for (int kk = 0; kk < 2; ++kk)                               \
  _Pragma("unroll") for (int mi = 0; mi < 4; ++mi)                               \
  _Pragma("unroll") for (int ni = 0; ni < 2; ++ni)                               \
    acc[(mh) * 4 + mi][(nh) * 2 + ni] = __builtin_amdgcn_mfma_f32_16x16x32_bf16( \
        af[mi][kk], bfr[ni][kk], acc[(mh) * 4 + mi][(nh) * 2 + ni], 0, 0, 0);    \
  __builtin_amdgcn_s_setprio(0);
#define PH_SYNC(cnt)                                                             \
  asm volatile("s_waitcnt vmcnt(" #cnt ")" ::: "memory");                        \
  __builtin_amdgcn_sched_barrier(0);                                             \
  __builtin_amdgcn_s_barrier();                                                  \
  __builtin_amdgcn_sched_barrier(0);

  for (int kt = 0; kt < nt - 1; ++kt) {
    const int c = kt & 1, o = c ^ 1;
    const int kn = (kt + 1) << 6;
    PH_SYNC(6) RDA256(c, 0) RDB256(c, 0) STG256(o, 0, kn) MFMA256(0, 0)
    PH_SYNC(6) RDB256(c, 1)              STG256(o, 1, kn) MFMA256(0, 1)
    PH_SYNC(6) RDA256(c, 1)              STG256(o, 2, kn) MFMA256(1, 1)
    PH_SYNC(6) RDB256(c, 0)              STG256(o, 3, kn) MFMA256(1, 0)
  }
  {
    const int c = (nt - 1) & 1;
    PH_SYNC(6) RDA256(c, 0) RDB256(c, 0) MFMA256(0, 0)
    PH_SYNC(4) RDB256(c, 1)              MFMA256(0, 1)
    PH_SYNC(2) RDA256(c, 1)              MFMA256(1, 1)
    PH_SYNC(0) RDB256(c, 0)              MFMA256(1, 0)
  }
#undef STG256
#undef RDA256
#undef RDB256
#undef MFMA256
#undef PH_SYNC

  // ---- epilogue: qkv scatter (block-uniform region: n0 is a multiple of 256) ----
  if (n0 < 1024) {                   // Q (pre-scaled)
#pragma unroll
    for (int MI = 0; MI < 8; ++MI)
#pragma unroll
      for (int NI = 0; NI < 4; ++NI)
#pragma unroll
        for (int r = 0; r < 4; ++r) {
          int m = m0 + wr * 128 + MI * 16 + lhi * 4 + r;
          int n = n0 + wc * 64 + NI * 16 + llo;
          int bidx = m >> 11, s = m & 2047, hh = n >> 6, dh = n & 63;
          qb[((size_t)(bidx * 16 + hh) * 2048 + s) * 64 + dh] =
              f2b((acc[MI][NI][r] + bias[n]) * SCL2E);
        }
  } else if (n0 < 2048) {            // K
#pragma unroll
    for (int MI = 0; MI < 8; ++MI)
#pragma unroll
      for (int NI = 0; NI < 4; ++NI)
#pragma unroll
        for (int r = 0; r < 4; ++r) {
          int m = m0 + wr * 128 + MI * 16 + lhi * 4 + r;
          int n = n0 + wc * 64 + NI * 16 + llo;
          int n2 = n - 1024;
          int bidx = m >> 11, s = m & 2047, hh = n2 >> 6, dh = n2 & 63;
          kb[((size_t)(bidx * 16 + hh) * 2048 + s) * 64 + dh] =
              f2b(acc[MI][NI][r] + bias[n]);
        }
  } else {                           // V^T, slot-permuted
#pragma unroll
    for (int MI = 0; MI < 8; ++MI)
#pragma unroll
      for (int NI = 0; NI < 4; ++NI)
#pragma unroll
        for (int r = 0; r < 4; ++r) {
          int m = m0 + wr * 128 + MI * 16 + lhi * 4 + r;
          int n = n0 + wc * 64 + NI * 16 + llo;
          int n2 = n - 2048;
          int bidx = m >> 11, s = m & 2047, hh = n2 >> 6, dh = n2 & 63;
          int col = (s & ~127) | ((s & 15) * 8 + ((s >> 4) & 7));
          vtb[((size_t)(bidx * 16 + hh) * 64 + dh) * 2048 + col] =
              f2b(acc[MI][NI][r] + bias[n]);
        }
  }
}

// ---------------- flash-style causal attention, 8-wave blocks (r14 proven) ----------------
__global__ __launch_bounds__(512) void attn128(
    const u16* __restrict__ Qb, const u16* __restrict__ Kb,
    const u16* __restrict__ VTb, u16* __restrict__ AO) {
  __shared__ __attribute__((aligned(16))) u16 kls[128 * 64];  // K tile  [128 kv][64 d]
  __shared__ __attribute__((aligned(16))) u16 vls[64 * 128];  // V^T tile [64 d][128 slot]
  __shared__ __attribute__((aligned(16))) u16 pl[8][16][136]; // P [wave][16 q][128 slot +8]
  const int t = threadIdx.x, w = t >> 6, lane = t & 63;
  const int lhi = lane >> 4, llo = lane & 15;

  // XCD-grouping swizzle (bijective): all 8 pr-blocks of a head share one XCD
  const int lin = blockIdx.y * 8 + blockIdx.x;
  const int bh = ((lin >> 6) << 3) | (lin & 7);
  const int pr = (lin >> 3) & 7;
  const int bb = bh >> 4, hh = bh & 15;

  const u16* Qp = Qb + (size_t)bh * (S_ * DH_);
  const u16* Kp = Kb + (size_t)bh * (S_ * DH_);
  const u16* Vp = VTb + (size_t)bh * (DH_ * S_);

  bf16x8 ones;
#pragma unroll
  for (int i = 0; i < 8; ++i) ones[i] = (short)0x3F80;

  int krow[2], kcolE[2], kdst[2], vrow[2], vcolE[2], vdst[2];
#pragma unroll
  for (int c = 0; c < 2; ++c) {
    int b = c * 8192 + t * 16;
    krow[c] = b >> 7;
    kcolE[c] = (b & 127) >> 1;
    kdst[c] = krow[c] * 128 + ((b & 127) ^ ((krow[c] & 7) << 4));
    vrow[c] = b >> 8;
    vcolE[c] = (b & 255) >> 1;
    vdst[c] = vrow[c] * 256 + ((b & 255) ^ ((vrow[c] & 15) << 4));
  }

  for (int ci = 0; ci < 2; ++ci) {
    const int qc = ci ? (15 - pr) : pr;
    const int q0 = qc * 128;
    const int qrow = q0 + w * 16 + llo;
    bf16x8 aq0 = *(const bf16x8*)(Qp + (size_t)qrow * DH_ + lhi * 8);
    bf16x8 aq1 = *(const bf16x8*)(Qp + (size_t)qrow * DH_ + 32 + lhi * 8);
    const int n128 = qc + 1;

    bf16x8 kst[2], vst[2];
#pragma unroll
    for (int c = 0; c < 2; ++c) {
      kst[c] = *(const bf16x8*)(Kp + (size_t)krow[c] * DH_ + kcolE[c]);
      vst[c] = *(const bf16x8*)(Vp + (size_t)vrow[c] * S_ + vcolE[c]);
    }
    __syncthreads();
#pragma unroll
    for (int c = 0; c < 2; ++c) {
      *(bf16x8*)((char*)kls + kdst[c]) = kst[c];
      *(bf16x8*)((char*)vls + vdst[c]) = vst[c];
    }
    __syncthreads();

    f32x4 o[4] = {};
    f32x4 osum = {};
    const int crow = q0 + w * 16 + lhi * 4;
    const int sw = (llo & 7) << 4;

    for (int tt = 0; tt < n128 - 1; ++tt) {
      const int kv0 = tt << 7;
#pragma unroll
      for (int c = 0; c < 2; ++c) {
        kst[c] = *(const bf16x8*)(Kp + (size_t)(kv0 + 128 + krow[c]) * DH_ + kcolE[c]);
        vst[c] = *(const bf16x8*)(Vp + (size_t)vrow[c] * S_ + kv0 + 128 + vcolE[c]);
      }

      f32x4 sc[8] = {};
      __builtin_amdgcn_s_setprio(1);
#pragma unroll
      for (int f = 0; f < 8; ++f) {
        const char* base = (const char*)kls + (f * 16 + llo) * 128;
        bf16x8 bk0 = *(const bf16x8*)(base + ((lhi * 16) ^ sw));
        bf16x8 bk1 = *(const bf16x8*)(base + ((64 + lhi * 16) ^ sw));
        sc[f] = __builtin_amdgcn_mfma_f32_16x16x32_bf16(aq0, bk0, sc[f], 0, 0, 0);
        sc[f] = __builtin_amdgcn_mfma_f32_16x16x32_bf16(aq1, bk1, sc[f], 0, 0, 0);
      }
      __builtin_amdgcn_s_setprio(0);

#pragma unroll
      for (int r = 0; r < 4; ++r) {
        float p[8];
#pragma unroll
        for (int f = 0; f < 8; ++f) p[f] = exp2f(sc[f][r]);
        u32x4 pw;
        pw[0] = cvt_pk_bf16(p[0], p[1]);
        pw[1] = cvt_pk_bf16(p[2], p[3]);
        pw[2] = cvt_pk_bf16(p[4], p[5]);
        pw[3] = cvt_pk_bf16(p[6], p[7]);
        *(u32x4*)((char*)&pl[w][lhi * 4 + r][0] + llo * 16) = pw;
      }

      __builtin_amdgcn_s_setprio(1);
#pragma unroll
      for (int kk = 0; kk < 4; ++kk) {
        bf16x8 ap = *(const bf16x8*)((const char*)&pl[w][llo][0] + kk * 64 + lhi * 16);
#pragma unroll
        for (int f = 0; f < 4; ++f) {
          const char* vbase = (const char*)vls + (f * 16 + llo) * 256;
          bf16x8 bv = *(const bf16x8*)(vbase + ((kk * 64 + lhi * 16) ^ (llo << 4)));
          o[f] = __builtin_amdgcn_mfma_f32_16x16x32_bf16(ap, bv, o[f], 0, 0, 0);
        }
        osum = __builtin_amdgcn_mfma_f32_16x16x32_bf16(ap, ones, osum, 0, 0, 0);
      }
      __builtin_amdgcn_s_setprio(0);

      __syncthreads();
#pragma unroll
      for (int c = 0; c < 2; ++c) {
        *(bf16x8*)((char*)kls + kdst[c]) = kst[c];
        *(bf16x8*)((char*)vls + vdst[c]) = vst[c];
      }
      __syncthreads();
    }

    { // diagonal tile (masked), no prefetch
      const int kv0 = (n128 - 1) << 7;
      f32x4 sc[8] = {};
      __builtin_amdgcn_s_setprio(1);
#pragma unroll
      for (int f = 0; f < 8; ++f) {
        const char* base = (const char*)kls + (f * 16 + llo) * 128;
        bf16x8 bk0 = *(const bf16x8*)(base + ((lhi * 16) ^ sw));
        bf16x8 bk1 = *(const bf16x8*)(base + ((64 + lhi * 16) ^ sw));
        sc[f] = __builtin_amdgcn_mfma_f32_16x16x32_bf16(aq0, bk0, sc[f], 0, 0, 0);
        sc[f] = __builtin_amdgcn_mfma_f32_16x16x32_bf16(aq1, bk1, sc[f], 0, 0, 0);
      }
      __builtin_amdgcn_s_setprio(0);

#pragma unroll
      for (int r = 0; r < 4; ++r) {
        float p[8];
#pragma unroll
        for (int f = 0; f < 8; ++f) {
          float x = sc[f][r];
          if (kv0 + f * 16 + llo > crow + r) x = -1e30f;
          p[f] = exp2f(x);
        }
        u32x4 pw;
        pw[0] = cvt_pk_bf16(p[0], p[1]);
        pw[1] = cvt_pk_bf16(p[2], p[3]);
        pw[2] = cvt_pk_bf16(p[4], p[5]);
        pw[3] = cvt_pk_bf16(p[6], p[7]);
        *(u32x4*)((char*)&pl[w][lhi * 4 + r][0] + llo * 16) = pw;
      }

      __builtin_amdgcn_s_setprio(1);
#pragma unroll
      for (int kk = 0; kk < 4; ++kk) {
        bf16x8 ap = *(const bf16x8*)((const char*)&pl[w][llo][0] + kk * 64 + lhi * 16);
#pragma unroll
        for (int f = 0; f < 4; ++f) {
          const char* vbase = (const char*)vls + (f * 16 + llo) * 256;
          bf16x8 bv = *(const bf16x8*)(vbase + ((kk * 64 + lhi * 16) ^ (llo << 4)));
          o[f] = __builtin_amdgcn_mfma_f32_16x16x32_bf16(ap, bv, o[f], 0, 0, 0);
        }
        osum = __builtin_amdgcn_mfma_f32_16x16x32_bf16(ap, ones, osum, 0, 0, 0);
      }
      __builtin_amdgcn_s_setprio(0);
    }

#pragma unroll
    for (int f = 0; f < 4; ++f)
#pragma unroll
      for (int r = 0; r < 4; ++r) {
        int row = crow + r;
        int dh = f * 16 + llo;
        float val = o[f][r] / osum[r];
        AO[((size_t)bb * S_ + row) * D_ + hh * DH_ + dh] = f2b(val);
      }
  }
}

extern "C" void kernel_launch(void* const* d_in, const int* in_sizes, int n_in,
                              void* d_out, int out_size, void* d_ws, size_t ws_size,
                              hipStream_t stream) {
  const float* x  = (const float*)d_in[0];
  const float* w1 = (const float*)d_in[1];
  const float* b1 = (const float*)d_in[2];
  const float* w2 = (const float*)d_in[3];
  const float* b2 = (const float*)d_in[4];
  float* out = (float*)d_out;
  char* ws = (char*)d_ws;

  u16* xb  = (u16*)(ws);                 // 16 MB (reused as AO after gemm1)
  u16* w1t = (u16*)(ws + 16777216);      // 6 MB
  u16* w2t = (u16*)(ws + 23068672);      // 2 MB
  u16* qb  = (u16*)(ws + 25165824);      // 16 MB
  u16* kb  = (u16*)(ws + 41943040);      // 16 MB
  u16* vtb = (u16*)(ws + 58720256);      // 16 MB
  u16* ao  = xb;

  cvt_f32_bf16<<<8192, 256, 0, stream>>>(x, xb, M_ * D_);
  transpose_cvt<<<dim3(96, 32), dim3(32, 8), 0, stream>>>(w1, w1t, 1024, 3072);
  transpose_cvt<<<dim3(32, 32), dim3(32, 8), 0, stream>>>(w2, w2t, 1024, 1024);

  gemm256<<<dim3(12, 32), 512, 0, stream>>>(xb, w1t, b1, qb, kb, vtb, 1024);
  attn128<<<dim3(8, 64), 512, 0, stream>>>(qb, kb, vtb, ao);
  gemm_bt<0><<<dim3(8, 64), 256, 0, stream>>>(ao, w2t, b2, out, nullptr, nullptr, nullptr, 1024, 1024);
}

// Round 16
// 182.356 us; speedup vs baseline: 1.1614x; 1.1614x over previous
//
#include <hip/hip_runtime.h>

typedef unsigned short u16;
typedef short bf16x8 __attribute__((ext_vector_type(8)));
typedef float f32x4 __attribute__((ext_vector_type(4)));
typedef unsigned int u32;
typedef u32 u32x4 __attribute__((ext_vector_type(4)));

#define B_ 4
#define S_ 2048
#define D_ 1024
#define H_ 16
#define DH_ 64
#define M_ 8192   // B*S
#define SCL2E 0.1803368801111244f  /* 0.125 * log2(e), folded into Q at gemm1 */

__device__ __forceinline__ u16 f2b(float f) {
  union { float f; unsigned int u; } v; v.f = f;
  unsigned int u = v.u;
  unsigned int r = (u + 0x7FFFu + ((u >> 16) & 1u)) >> 16;
  return (u16)r;
}

// async global->LDS, 16B per lane; lds dst is wave-uniform base + lane*16
__device__ __forceinline__ void gload16(const void* g, void* l) {
  __builtin_amdgcn_global_load_lds(
      (const __attribute__((address_space(1))) unsigned int*)g,
      (__attribute__((address_space(3))) unsigned int*)l,
      16, 0, 0);
}

// pack two f32 -> two bf16 (RNE) in one VALU op
__device__ __forceinline__ u32 cvt_pk_bf16(float lo, float hi) {
  u32 r;
  asm("v_cvt_pk_bf16_f32 %0, %1, %2" : "=v"(r) : "v"(lo), "v"(hi));
  return r;
}

// ---------------- fused preprocessing: one kernel, three block ranges ----------------
// [0,2048)        : x f32 -> bf16, grid-stride over 2M float4 groups
// [2048,5120)     : w1 [1024][3072] -> w1t [3072][1024] bf16 (32x32 tiles, 96x32)
// [5120,6144)     : w2 [1024][1024] -> w2t [1024][1024] bf16 (32x32 tiles, 32x32)
struct __attribute__((aligned(8))) u16x4 { u16 x, y, z, w; };

__global__ __launch_bounds__(256) void prep_fused(
    const float* __restrict__ x, u16* __restrict__ xb,
    const float* __restrict__ w1, u16* __restrict__ w1t,
    const float* __restrict__ w2, u16* __restrict__ w2t) {
  __shared__ float tile[32][33];
  const int bid = blockIdx.x, t = threadIdx.x;

  if (bid < 2048) {
    // ---- cvt x: n = M_*D_ = 8388608 elems ----
    const int n = M_ * D_;
    for (int i = (bid * 256 + t) * 4; i < n; i += 2048 * 256 * 4) {
      float4 v = *(const float4*)(x + i);
      u16x4 o; o.x = f2b(v.x); o.y = f2b(v.y); o.z = f2b(v.z); o.w = f2b(v.w);
      *(u16x4*)(xb + i) = o;
    }
    return;
  }

  const float* in;  u16* outp;  int R, C, bx, by;
  if (bid < 5120) {
    int rel = bid - 2048; bx = rel % 96; by = rel / 96;
    in = w1; outp = w1t; R = 1024; C = 3072;
  } else {
    int rel = bid - 5120; bx = rel % 32; by = rel / 32;
    in = w2; outp = w2t; R = 1024; C = 1024;
  }
  const int c0 = bx * 32, r0 = by * 32;
  const int tx = t & 31, ty = t >> 5;   // 32 x 8
#pragma unroll
  for (int j = 0; j < 32; j += 8)
    tile[ty + j][tx] = in[(size_t)(r0 + ty + j) * C + c0 + tx];
  __syncthreads();
#pragma unroll
  for (int j = 0; j < 32; j += 8)
    outp[(size_t)(c0 + ty + j) * R + r0 + tx] = f2b(tile[tx][ty + j]);
}

// ---------------- bf16 GEMM: A[M][K] @ BT[N][K]^T + bias (r12/r14 proven) ----------------
// 4-wave 128x128, BK=64, LDS double-buffered. Counted vmcnt: STAGE(nxt) at loop
// top, s_waitcnt vmcnt(8), raw s_barrier publish, ds_read+MFMA, raw s_barrier.
// Pre-swizzled global source, XOR on read. XCD block swizzle.
// MODE 0: fp32 out. MODE 1: qkv scatter (Q pre-scaled, V^T slot-permuted:
//   slot(s) = (s&15)*8 + ((s>>4)&7)).
template <int MODE>
__global__ __launch_bounds__(256) void gemm_bt(
    const u16* __restrict__ A, const u16* __restrict__ BT,
    const float* __restrict__ bias, float* __restrict__ outf,
    u16* __restrict__ qb, u16* __restrict__ kb, u16* __restrict__ vtb,
    int Ncols, int Kdim) {
  __shared__ __attribute__((aligned(16))) u16 lsA[2][128 * 64];
  __shared__ __attribute__((aligned(16))) u16 lsB[2][128 * 64];
  const int t = threadIdx.x;
  const int lane = t & 63, w = t >> 6;
  const int lhi = lane >> 4, llo = lane & 15;

  const int gx = gridDim.x;
  const int lin = blockIdx.y * gx + blockIdx.x;
  const int nwg = gx * gridDim.y;
  const int sw = (lin & 7) * (nwg >> 3) + (lin >> 3);
  const int m0 = (sw / gx) * 128, n0 = (sw % gx) * 128;

  const int wr = (w >> 1) * 64, wc = (w & 1) * 64;

  const int r8 = lane >> 3;
  const int scolE = ((lane & 7) ^ r8) * 8;
  const int srow = w * 32 + r8;

  f32x4 acc[4][4] = {};
  const int nt = Kdim >> 6;

#define STAGE_G(buf, kk0)                                                        \
  _Pragma("unroll") for (int j = 0; j < 4; ++j) {                                \
    gload16(A + (size_t)(m0 + srow + j * 8) * Kdim + (kk0) + scolE,              \
            &lsA[buf][(w * 32 + j * 8) * 64]);                                   \
    gload16(BT + (size_t)(n0 + srow + j * 8) * Kdim + (kk0) + scolE,             \
            &lsB[buf][(w * 32 + j * 8) * 64]);                                   \
  }

  STAGE_G(0, 0)                       // 8 loads/wave in flight

  for (int tt = 0; tt < nt; ++tt) {
    const int cur = tt & 1;
    if (tt + 1 < nt) {
      STAGE_G(cur ^ 1, (tt + 1) << 6)                     // +8 newer loads
      asm volatile("s_waitcnt vmcnt(8)" ::: "memory");    // own cur loads done
    } else {
      asm volatile("s_waitcnt vmcnt(0)" ::: "memory");
    }
    __builtin_amdgcn_sched_barrier(0);
    __builtin_amdgcn_s_barrier();     // publish cur tile (no drain)
    __builtin_amdgcn_sched_barrier(0);
#pragma unroll
    for (int kk = 0; kk < 2; ++kk) {
      bf16x8 af[4], bfr[4];
#pragma unroll
      for (int i = 0; i < 4; ++i) {
        int ra = wr + i * 16 + llo;
        af[i] = *(const bf16x8*)((const char*)&lsA[cur][ra * 64] +
                                 ((kk * 64 + lhi * 16) ^ ((ra & 7) << 4)));
        int rb = wc + i * 16 + llo;
        bfr[i] = *(const bf16x8*)((const char*)&lsB[cur][rb * 64] +
                                  ((kk * 64 + lhi * 16) ^ ((rb & 7) << 4)));
      }
#pragma unroll
      for (int mi = 0; mi < 4; ++mi)
#pragma unroll
        for (int ni = 0; ni < 4; ++ni)
          acc[mi][ni] = __builtin_amdgcn_mfma_f32_16x16x32_bf16(af[mi], bfr[ni], acc[mi][ni], 0, 0, 0);
    }
    __builtin_amdgcn_sched_barrier(0);
    __builtin_amdgcn_s_barrier();     // reads of cur done before next overwrite
  }
#undef STAGE_G

  if (MODE == 0) {
#pragma unroll
    for (int mi = 0; mi < 4; ++mi)
#pragma unroll
      for (int ni = 0; ni < 4; ++ni)
#pragma unroll
        for (int r = 0; r < 4; ++r) {
          int m = m0 + wr + mi * 16 + lhi * 4 + r;
          int n = n0 + wc + ni * 16 + llo;
          outf[(size_t)m * Ncols + n] = acc[mi][ni][r] + bias[n];
        }
  } else if (n0 < 1024) {            // Q (pre-scaled)
#pragma unroll
    for (int mi = 0; mi < 4; ++mi)
#pragma unroll
      for (int ni = 0; ni < 4; ++ni)
#pragma unroll
        for (int r = 0; r < 4; ++r) {
          int m = m0 + wr + mi * 16 + lhi * 4 + r;
          int n = n0 + wc + ni * 16 + llo;
          int bidx = m >> 11, s = m & 2047, hh = n >> 6, dh = n & 63;
          qb[((size_t)(bidx * 16 + hh) * 2048 + s) * 64 + dh] =
              f2b((acc[mi][ni][r] + bias[n]) * SCL2E);
        }
  } else if (n0 < 2048) {            // K
#pragma unroll
    for (int mi = 0; mi < 4; ++mi)
#pragma unroll
      for (int ni = 0; ni < 4; ++ni)
#pragma unroll
        for (int r = 0; r < 4; ++r) {
          int m = m0 + wr + mi * 16 + lhi * 4 + r;
          int n2 = n0 - 1024 + wc + ni * 16 + llo;
          int bidx = m >> 11, s = m & 2047, hh = n2 >> 6, dh = n2 & 63;
          kb[((size_t)(bidx * 16 + hh) * 2048 + s) * 64 + dh] =
              f2b(acc[mi][ni][r] + bias[n0 + wc + ni * 16 + llo]);
        }
  } else {                           // V^T, slot-permuted
#pragma unroll
    for (int mi = 0; mi < 4; ++mi)
#pragma unroll
      for (int ni = 0; ni < 4; ++ni)
#pragma unroll
        for (int r = 0; r < 4; ++r) {
          int m = m0 + wr + mi * 16 + lhi * 4 + r;
          int n2 = n0 - 2048 + wc + ni * 16 + llo;
          int bidx = m >> 11, s = m & 2047, hh = n2 >> 6, dh = n2 & 63;
          int col = (s & ~127) | ((s & 15) * 8 + ((s >> 4) & 7));
          vtb[((size_t)(bidx * 16 + hh) * 64 + dh) * 2048 + col] =
              f2b(acc[mi][ni][r] + bias[n0 + wc + ni * 16 + llo]);
        }
  }
}

// ---------------- flash-style causal attention, 8-wave blocks (r14 proven) ----------------
// grid: (8, B*H), 512 threads. XCD-grouping swizzle: all 8 pr-blocks of one
// head share one XCD (K/V L2-local; FETCH 133->24.6 MB measured). Mask hoisted.
// K,V^T staged in LDS (single-buffer, reg-bridge prefetch at loop top).
// No max-tracking; exp2 domain; row-sum via ones-MFMA.
__global__ __launch_bounds__(512) void attn128(
    const u16* __restrict__ Qb, const u16* __restrict__ Kb,
    const u16* __restrict__ VTb, u16* __restrict__ AO) {
  __shared__ __attribute__((aligned(16))) u16 kls[128 * 64];  // K tile  [128 kv][64 d]
  __shared__ __attribute__((aligned(16))) u16 vls[64 * 128];  // V^T tile [64 d][128 slot]
  __shared__ __attribute__((aligned(16))) u16 pl[8][16][136]; // P [wave][16 q][128 slot +8]
  const int t = threadIdx.x, w = t >> 6, lane = t & 63;
  const int lhi = lane >> 4, llo = lane & 15;

  // XCD-grouping swizzle (bijective): lin -> bh = (lin>>6)*8 + (lin&7), pr = (lin>>3)&7
  const int lin = blockIdx.y * 8 + blockIdx.x;
  const int bh = ((lin >> 6) << 3) | (lin & 7);
  const int pr = (lin >> 3) & 7;
  const int bb = bh >> 4, hh = bh & 15;

  const u16* Qp = Qb + (size_t)bh * (S_ * DH_);
  const u16* Kp = Kb + (size_t)bh * (S_ * DH_);
  const u16* Vp = VTb + (size_t)bh * (DH_ * S_);

  bf16x8 ones;
#pragma unroll
  for (int i = 0; i < 8; ++i) ones[i] = (short)0x3F80;

  int krow[2], kcolE[2], kdst[2], vrow[2], vcolE[2], vdst[2];
#pragma unroll
  for (int c = 0; c < 2; ++c) {
    int b = c * 8192 + t * 16;
    krow[c] = b >> 7;
    kcolE[c] = (b & 127) >> 1;
    kdst[c] = krow[c] * 128 + ((b & 127) ^ ((krow[c] & 7) << 4));
    vrow[c] = b >> 8;
    vcolE[c] = (b & 255) >> 1;
    vdst[c] = vrow[c] * 256 + ((b & 255) ^ ((vrow[c] & 15) << 4));
  }

  for (int ci = 0; ci < 2; ++ci) {
    const int qc = ci ? (15 - pr) : pr;
    const int q0 = qc * 128;
    const int qrow = q0 + w * 16 + llo;
    bf16x8 aq0 = *(const bf16x8*)(Qp + (size_t)qrow * DH_ + lhi * 8);
    bf16x8 aq1 = *(const bf16x8*)(Qp + (size_t)qrow * DH_ + 32 + lhi * 8);
    const int n128 = qc + 1;

    bf16x8 kst[2], vst[2];
#pragma unroll
    for (int c = 0; c < 2; ++c) {
      kst[c] = *(const bf16x8*)(Kp + (size_t)krow[c] * DH_ + kcolE[c]);
      vst[c] = *(const bf16x8*)(Vp + (size_t)vrow[c] * S_ + vcolE[c]);
    }
    __syncthreads();
#pragma unroll
    for (int c = 0; c < 2; ++c) {
      *(bf16x8*)((char*)kls + kdst[c]) = kst[c];
      *(bf16x8*)((char*)vls + vdst[c]) = vst[c];
    }
    __syncthreads();

    f32x4 o[4] = {};
    f32x4 osum = {};
    const int crow = q0 + w * 16 + lhi * 4;
    const int sw = (llo & 7) << 4;

    for (int tt = 0; tt < n128 - 1; ++tt) {
      const int kv0 = tt << 7;
#pragma unroll
      for (int c = 0; c < 2; ++c) {
        kst[c] = *(const bf16x8*)(Kp + (size_t)(kv0 + 128 + krow[c]) * DH_ + kcolE[c]);
        vst[c] = *(const bf16x8*)(Vp + (size_t)vrow[c] * S_ + kv0 + 128 + vcolE[c]);
      }

      f32x4 sc[8] = {};
      __builtin_amdgcn_s_setprio(1);
#pragma unroll
      for (int f = 0; f < 8; ++f) {
        const char* base = (const char*)kls + (f * 16 + llo) * 128;
        bf16x8 bk0 = *(const bf16x8*)(base + ((lhi * 16) ^ sw));
        bf16x8 bk1 = *(const bf16x8*)(base + ((64 + lhi * 16) ^ sw));
        sc[f] = __builtin_amdgcn_mfma_f32_16x16x32_bf16(aq0, bk0, sc[f], 0, 0, 0);
        sc[f] = __builtin_amdgcn_mfma_f32_16x16x32_bf16(aq1, bk1, sc[f], 0, 0, 0);
      }
      __builtin_amdgcn_s_setprio(0);

#pragma unroll
      for (int r = 0; r < 4; ++r) {
        float p[8];
#pragma unroll
        for (int f = 0; f < 8; ++f) p[f] = exp2f(sc[f][r]);
        u32x4 pw;
        pw[0] = cvt_pk_bf16(p[0], p[1]);
        pw[1] = cvt_pk_bf16(p[2], p[3]);
        pw[2] = cvt_pk_bf16(p[4], p[5]);
        pw[3] = cvt_pk_bf16(p[6], p[7]);
        *(u32x4*)((char*)&pl[w][lhi * 4 + r][0] + llo * 16) = pw;
      }

      __builtin_amdgcn_s_setprio(1);
#pragma unroll
      for (int kk = 0; kk < 4; ++kk) {
        bf16x8 ap = *(const bf16x8*)((const char*)&pl[w][llo][0] + kk * 64 + lhi * 16);
#pragma unroll
        for (int f = 0; f < 4; ++f) {
          const char* vbase = (const char*)vls + (f * 16 + llo) * 256;
          bf16x8 bv = *(const bf16x8*)(vbase + ((kk * 64 + lhi * 16) ^ (llo << 4)));
          o[f] = __builtin_amdgcn_mfma_f32_16x16x32_bf16(ap, bv, o[f], 0, 0, 0);
        }
        osum = __builtin_amdgcn_mfma_f32_16x16x32_bf16(ap, ones, osum, 0, 0, 0);
      }
      __builtin_amdgcn_s_setprio(0);

      __syncthreads();
#pragma unroll
      for (int c = 0; c < 2; ++c) {
        *(bf16x8*)((char*)kls + kdst[c]) = kst[c];
        *(bf16x8*)((char*)vls + vdst[c]) = vst[c];
      }
      __syncthreads();
    }

    { // diagonal tile (masked), no prefetch
      const int kv0 = (n128 - 1) << 7;
      f32x4 sc[8] = {};
      __builtin_amdgcn_s_setprio(1);
#pragma unroll
      for (int f = 0; f < 8; ++f) {
        const char* base = (const char*)kls + (f * 16 + llo) * 128;
        bf16x8 bk0 = *(const bf16x8*)(base + ((lhi * 16) ^ sw));
        bf16x8 bk1 = *(const bf16x8*)(base + ((64 + lhi * 16) ^ sw));
        sc[f] = __builtin_amdgcn_mfma_f32_16x16x32_bf16(aq0, bk0, sc[f], 0, 0, 0);
        sc[f] = __builtin_amdgcn_mfma_f32_16x16x32_bf16(aq1, bk1, sc[f], 0, 0, 0);
      }
      __builtin_amdgcn_s_setprio(0);

#pragma unroll
      for (int r = 0; r < 4; ++r) {
        float p[8];
#pragma unroll
        for (int f = 0; f < 8; ++f) {
          float x = sc[f][r];
          if (kv0 + f * 16 + llo > crow + r) x = -1e30f;
          p[f] = exp2f(x);
        }
        u32x4 pw;
        pw[0] = cvt_pk_bf16(p[0], p[1]);
        pw[1] = cvt_pk_bf16(p[2], p[3]);
        pw[2] = cvt_pk_bf16(p[4], p[5]);
        pw[3] = cvt_pk_bf16(p[6], p[7]);
        *(u32x4*)((char*)&pl[w][lhi * 4 + r][0] + llo * 16) = pw;
      }

      __builtin_amdgcn_s_setprio(1);
#pragma unroll
      for (int kk = 0; kk < 4; ++kk) {
        bf16x8 ap = *(const bf16x8*)((const char*)&pl[w][llo][0] + kk * 64 + lhi * 16);
#pragma unroll
        for (int f = 0; f < 4; ++f) {
          const char* vbase = (const char*)vls + (f * 16 + llo) * 256;
          bf16x8 bv = *(const bf16x8*)(vbase + ((kk * 64 + lhi * 16) ^ (llo << 4)));
          o[f] = __builtin_amdgcn_mfma_f32_16x16x32_bf16(ap, bv, o[f], 0, 0, 0);
        }
        osum = __builtin_amdgcn_mfma_f32_16x16x32_bf16(ap, ones, osum, 0, 0, 0);
      }
      __builtin_amdgcn_s_setprio(0);
    }

#pragma unroll
    for (int f = 0; f < 4; ++f)
#pragma unroll
      for (int r = 0; r < 4; ++r) {
        int row = crow + r;
        int dh = f * 16 + llo;
        float val = o[f][r] / osum[r];
        AO[((size_t)bb * S_ + row) * D_ + hh * DH_ + dh] = f2b(val);
      }
  }
}

extern "C" void kernel_launch(void* const* d_in, const int* in_sizes, int n_in,
                              void* d_out, int out_size, void* d_ws, size_t ws_size,
                              hipStream_t stream) {
  const float* x  = (const float*)d_in[0];
  const float* w1 = (const float*)d_in[1];
  const float* b1 = (const float*)d_in[2];
  const float* w2 = (const float*)d_in[3];
  const float* b2 = (const float*)d_in[4];
  float* out = (float*)d_out;
  char* ws = (char*)d_ws;

  u16* xb  = (u16*)(ws);                 // 16 MB (reused as AO after gemm1)
  u16* w1t = (u16*)(ws + 16777216);      // 6 MB
  u16* w2t = (u16*)(ws + 23068672);      // 2 MB
  u16* qb  = (u16*)(ws + 25165824);      // 16 MB
  u16* kb  = (u16*)(ws + 41943040);      // 16 MB
  u16* vtb = (u16*)(ws + 58720256);      // 16 MB
  u16* ao  = xb;

  prep_fused<<<6144, 256, 0, stream>>>(x, xb, w1, w1t, w2, w2t);

  gemm_bt<1><<<dim3(24, 64), 256, 0, stream>>>(xb, w1t, b1, nullptr, qb, kb, vtb, 3072, 1024);
  attn128<<<dim3(8, 64), 512, 0, stream>>>(qb, kb, vtb, ao);
  gemm_bt<0><<<dim3(8, 64), 256, 0, stream>>>(ao, w2t, b2, out, nullptr, nullptr, nullptr, 1024, 1024);
}